// Round 1
// baseline (1517.640 us; speedup 1.0000x reference)
//
#include <hip/hip_runtime.h>
#include <hip/hip_bf16.h>

#define L_Q 49
#define D_MODEL 256
#define NHEAD 8
#define DK 32
#define PP 41
#define POS_OFF 20

__device__ __forceinline__ float bf2f(unsigned short u) {
    return __uint_as_float(((unsigned)u) << 16);
}
__device__ __forceinline__ unsigned short f2bf(float f) {
    __hip_bfloat16 h = __float2bfloat16(f);
    return *reinterpret_cast<unsigned short*>(&h);
}

// ---------------- k_pos prep: k_posy[p,d] = sum_f pos_y[p,f] * w_k[d,f]
//                  k_posx[p,d] = sum_f pos_x[p,f] * w_k[d,128+f]
// kpos layout: [2][41][256] fp32, 0 = y, 1 = x
__global__ __launch_bounds__(256)
void prep_kpos(const float* __restrict__ pos_y, const float* __restrict__ pos_x,
               const float* __restrict__ W, float* __restrict__ kpos) {
    int p = blockIdx.x;          // 0..40
    int which = blockIdx.y;      // 0=y, 1=x
    __shared__ float pr[128];
    int d = threadIdx.x;         // 0..255
    if (d < 128) pr[d] = which ? pos_x[p * 128 + d] : pos_y[p * 128 + d];
    __syncthreads();
    const float* Wk = W + 256 * 256;  // w_k rows
    int fOff = which ? 128 : 0;
    float acc = 0.f;
    #pragma unroll 8
    for (int f = 0; f < 128; ++f)
        acc += pr[f] * Wk[(size_t)d * 256 + fOff + f];
    kpos[((size_t)which * PP + p) * 256 + d] = acc;
}

// ---------------- projection GEMM: out[m,n] = (sum_k X[m,k]*W[n,k] + b[n]) * scale
// X fp32 [M][256], W fp32 (rows are output features), out bf16 [M][256]
__global__ __launch_bounds__(256)
void proj_gemm(const float* __restrict__ X, const float* __restrict__ W,
               const float* __restrict__ bias, float scale,
               unsigned short* __restrict__ out, int M) {
    const int BM = 64, BN = 64, BK = 32;
    __shared__ float Xs[BM][BK + 1];
    __shared__ float Ws[BN][BK + 1];
    int row0 = blockIdx.x * BM, col0 = blockIdx.y * BN;
    int tid = threadIdx.x;
    int ty = tid >> 4, tx = tid & 15;
    float acc[4][4] = {};
    for (int k0 = 0; k0 < 256; k0 += BK) {
        #pragma unroll
        for (int t = 0; t < 2; ++t) {
            int e = tid + t * 256;       // 512 float4 loads per tile
            int r = e >> 3;
            int c = (e & 7) * 4;
            int rr = row0 + r; if (rr >= M) rr = M - 1;
            float4 xv = *reinterpret_cast<const float4*>(&X[(size_t)rr * 256 + k0 + c]);
            Xs[r][c] = xv.x; Xs[r][c+1] = xv.y; Xs[r][c+2] = xv.z; Xs[r][c+3] = xv.w;
            float4 wv = *reinterpret_cast<const float4*>(&W[(size_t)(col0 + r) * 256 + k0 + c]);
            Ws[r][c] = wv.x; Ws[r][c+1] = wv.y; Ws[r][c+2] = wv.z; Ws[r][c+3] = wv.w;
        }
        __syncthreads();
        #pragma unroll
        for (int kk = 0; kk < BK; ++kk) {
            float xa[4], wb[4];
            #pragma unroll
            for (int i = 0; i < 4; ++i) xa[i] = Xs[ty * 4 + i][kk];
            #pragma unroll
            for (int j = 0; j < 4; ++j) wb[j] = Ws[tx * 4 + j][kk];
            #pragma unroll
            for (int i = 0; i < 4; ++i)
                #pragma unroll
                for (int j = 0; j < 4; ++j) acc[i][j] += xa[i] * wb[j];
        }
        __syncthreads();
    }
    #pragma unroll
    for (int i = 0; i < 4; ++i) {
        int row = row0 + ty * 4 + i;
        if (row >= M) continue;
        ushort4 pk;
        int n0 = col0 + tx * 4;
        pk.x = f2bf((acc[i][0] + bias[n0 + 0]) * scale);
        pk.y = f2bf((acc[i][1] + bias[n0 + 1]) * scale);
        pk.z = f2bf((acc[i][2] + bias[n0 + 2]) * scale);
        pk.w = f2bf((acc[i][3] + bias[n0 + 3]) * scale);
        *reinterpret_cast<ushort4*>(&out[(size_t)row * 256 + n0]) = pk;
    }
}

// ---------------- fused attention per (b,h) block
__global__ __launch_bounds__(256)
void attn_kernel(const unsigned short* __restrict__ qbuf,
                 const unsigned short* __restrict__ kbuf,
                 const unsigned short* __restrict__ vbuf,
                 const float* __restrict__ kpos,
                 const unsigned char* __restrict__ mask,
                 unsigned short* __restrict__ ctx,   // aliases qbuf (safe: per-block region)
                 int B) {
    int b = blockIdx.x, h = blockIdx.y;
    __shared__ float Qs[L_Q][DK + 1], Ks[L_Q][DK + 1], Vs[L_Q][DK + 1];
    __shared__ float kpy[PP][DK + 1], kpx[PP][DK + 1];
    __shared__ float S[L_Q][L_Q + 1];
    __shared__ int yy[L_Q], xx[L_Q];
    __shared__ unsigned char mb[64];
    int tid = threadIdx.x;

    if (tid < L_Q) mb[tid] = mask[(size_t)b * L_Q + tid];
    __syncthreads();
    if (tid < L_Q) {
        int r = tid / 7, c = tid % 7;
        int sy = 0, sx = 0;
        for (int rr = 0; rr <= r; ++rr) sy += (mb[rr * 7 + c] == 0);
        for (int cc = 0; cc <= c; ++cc) sx += (mb[r * 7 + cc] == 0);
        yy[tid] = sy; xx[tid] = sx;
    }

    size_t base = (size_t)b * D_MODEL + (size_t)h * DK;
    size_t lstride = (size_t)B * D_MODEL;
    for (int e = tid; e < L_Q * DK; e += 256) {
        int l = e >> 5, d = e & 31;
        size_t off = (size_t)l * lstride + base + d;
        Qs[l][d] = bf2f(qbuf[off]);
        Ks[l][d] = bf2f(kbuf[off]);
        Vs[l][d] = bf2f(vbuf[off]);
    }
    for (int e = tid; e < PP * DK; e += 256) {
        int p = e >> 5, d = e & 31;
        kpy[p][d] = kpos[(size_t)p * D_MODEL + h * DK + d];
        kpx[p][d] = kpos[((size_t)PP + p) * D_MODEL + h * DK + d];
    }
    __syncthreads();

    // logits: S[l][s] = sum_d Q[l][d] * (K[s][d] + kpy[iy][d] + kpx[ix][d])
    for (int e = tid; e < L_Q * L_Q; e += 256) {
        int l = e / L_Q, s = e - l * L_Q;
        int iy = yy[l] - yy[s] + POS_OFF;
        int ix = xx[l] - xx[s] + POS_OFF;
        float acc = 0.f;
        #pragma unroll 8
        for (int d = 0; d < DK; ++d) {
            float t = Ks[s][d] + kpy[iy][d] + kpx[ix][d];
            acc += Qs[l][d] * t;
        }
        if (mb[s]) acc = -1e30f;
        S[l][s] = acc;
    }
    __syncthreads();

    // row softmax (thread per row)
    if (tid < L_Q) {
        float m = -1e30f;
        for (int s = 0; s < L_Q; ++s) m = fmaxf(m, S[tid][s]);
        float sum = 0.f;
        for (int s = 0; s < L_Q; ++s) {
            float ex = expf(S[tid][s] - m);
            S[tid][s] = ex; sum += ex;
        }
        float inv = 1.f / sum;
        for (int s = 0; s < L_Q; ++s) S[tid][s] *= inv;
    }
    __syncthreads();

    // out: ctx[l, b, h*32+d] = sum_s P[l][s] * V[s][d]
    for (int e = tid; e < L_Q * DK; e += 256) {
        int l = e >> 5, d = e & 31;
        float acc = 0.f;
        #pragma unroll 7
        for (int s = 0; s < L_Q; ++s) acc += S[l][s] * Vs[s][d];
        size_t off = (size_t)l * lstride + base + d;
        ctx[off] = f2bf(acc);
    }
}

// ---------------- output projection: out[m,e] = sum_d ctx[m,d]*out_w[e,d] + out_b[e]
__global__ __launch_bounds__(256)
void out_gemm(const unsigned short* __restrict__ X, const float* __restrict__ W,
              const float* __restrict__ bias, float* __restrict__ out, int M) {
    const int BM = 64, BN = 64, BK = 32;
    __shared__ float Xs[BM][BK + 1];
    __shared__ float Ws[BN][BK + 1];
    int row0 = blockIdx.x * BM, col0 = blockIdx.y * BN;
    int tid = threadIdx.x;
    int ty = tid >> 4, tx = tid & 15;
    float acc[4][4] = {};
    for (int k0 = 0; k0 < 256; k0 += BK) {
        #pragma unroll
        for (int t = 0; t < 4; ++t) {        // 1024 ushort2 loads for X tile
            int e = tid + t * 256;
            int r = e >> 4;
            int c = (e & 15) * 2;
            int rr = row0 + r; if (rr >= M) rr = M - 1;
            ushort2 xv = *reinterpret_cast<const ushort2*>(&X[(size_t)rr * 256 + k0 + c]);
            Xs[r][c] = bf2f(xv.x); Xs[r][c + 1] = bf2f(xv.y);
        }
        #pragma unroll
        for (int t = 0; t < 2; ++t) {
            int e = tid + t * 256;
            int r = e >> 3;
            int c = (e & 7) * 4;
            float4 wv = *reinterpret_cast<const float4*>(&W[(size_t)(col0 + r) * 256 + k0 + c]);
            Ws[r][c] = wv.x; Ws[r][c+1] = wv.y; Ws[r][c+2] = wv.z; Ws[r][c+3] = wv.w;
        }
        __syncthreads();
        #pragma unroll
        for (int kk = 0; kk < BK; ++kk) {
            float xa[4], wb[4];
            #pragma unroll
            for (int i = 0; i < 4; ++i) xa[i] = Xs[ty * 4 + i][kk];
            #pragma unroll
            for (int j = 0; j < 4; ++j) wb[j] = Ws[tx * 4 + j][kk];
            #pragma unroll
            for (int i = 0; i < 4; ++i)
                #pragma unroll
                for (int j = 0; j < 4; ++j) acc[i][j] += xa[i] * wb[j];
        }
        __syncthreads();
    }
    #pragma unroll
    for (int i = 0; i < 4; ++i) {
        int row = row0 + ty * 4 + i;
        if (row >= M) continue;
        int n0 = col0 + tx * 4;
        float4 o;
        o.x = acc[i][0] + bias[n0 + 0];
        o.y = acc[i][1] + bias[n0 + 1];
        o.z = acc[i][2] + bias[n0 + 2];
        o.w = acc[i][3] + bias[n0 + 3];
        *reinterpret_cast<float4*>(&out[(size_t)row * 256 + n0]) = o;
    }
}

extern "C" void kernel_launch(void* const* d_in, const int* in_sizes, int n_in,
                              void* d_out, int out_size, void* d_ws, size_t ws_size,
                              hipStream_t stream) {
    const float* query = (const float*)d_in[0];
    const float* key   = (const float*)d_in[1];
    const float* value = (const float*)d_in[2];
    const unsigned char* maskp = (const unsigned char*)d_in[3];
    const float* W     = (const float*)d_in[4];   // (768,256)
    const float* bias  = (const float*)d_in[5];   // (768,)
    const float* out_w = (const float*)d_in[6];   // (256,256)
    const float* out_b = (const float*)d_in[7];   // (256,)
    const float* pos_x = (const float*)d_in[8];   // (41,128)
    const float* pos_y = (const float*)d_in[9];   // (41,128)
    float* out = (float*)d_out;

    int B = in_sizes[0] / (L_Q * D_MODEL);        // 2048
    int M = L_Q * B;                              // 100352

    size_t nqkv = (size_t)M * D_MODEL;            // elems per tensor
    unsigned short* qb = (unsigned short*)d_ws;
    unsigned short* kb = qb + nqkv;
    unsigned short* vb = kb + nqkv;
    float* kpos = (float*)(vb + nqkv);            // [2][41][256]

    const float scaling = 0.17677669529663687f;   // 1/sqrt(32)

    prep_kpos<<<dim3(PP, 2), 256, 0, stream>>>(pos_y, pos_x, W, kpos);

    dim3 ggrid((M + 63) / 64, 4);
    proj_gemm<<<ggrid, 256, 0, stream>>>(query, W,             bias,       scaling, qb, M);
    proj_gemm<<<ggrid, 256, 0, stream>>>(key,   W + 256 * 256, bias + 256, 1.0f,    kb, M);
    proj_gemm<<<ggrid, 256, 0, stream>>>(value, W + 512 * 256, bias + 512, 1.0f,    vb, M);

    attn_kernel<<<dim3(B, NHEAD), 256, 0, stream>>>(qb, kb, vb, kpos, maskp, qb, B);

    out_gemm<<<ggrid, 256, 0, stream>>>(qb, out_w, out_b, out, M);
}

// Round 2
// 1189.577 us; speedup vs baseline: 1.2758x; 1.2758x over previous
//
#include <hip/hip_runtime.h>
#include <hip/hip_bf16.h>

#define L_Q 49
#define D_MODEL 256
#define NHEAD 8
#define DK 32
#define PP 41
#define POS_OFF 20

typedef __attribute__((ext_vector_type(8))) __bf16 bf16x8;
typedef __attribute__((ext_vector_type(4))) float f32x4;
typedef __attribute__((ext_vector_type(8))) unsigned short u16x8;

__device__ __forceinline__ float bf2f(unsigned short u) {
    return __uint_as_float(((unsigned)u) << 16);
}
__device__ __forceinline__ unsigned short f2bf(float f) {
    unsigned u = __float_as_uint(f);
    return (unsigned short)((u + 0x7FFF + ((u >> 16) & 1)) >> 16);
}

// ---------------- one-time W conversion to bf16: W(768x256) then out_w(256x256)
__global__ __launch_bounds__(256)
void convert_w(const float* __restrict__ W, const float* __restrict__ out_w,
               unsigned short* __restrict__ wbf, unsigned short* __restrict__ owbf) {
    int i = blockIdx.x * 256 + threadIdx.x;   // 65536 float4 total
    if (i < 49152) {
        float4 v = reinterpret_cast<const float4*>(W)[i];
        ushort4 o = { f2bf(v.x), f2bf(v.y), f2bf(v.z), f2bf(v.w) };
        reinterpret_cast<ushort4*>(wbf)[i] = o;
    } else {
        float4 v = reinterpret_cast<const float4*>(out_w)[i - 49152];
        ushort4 o = { f2bf(v.x), f2bf(v.y), f2bf(v.z), f2bf(v.w) };
        reinterpret_cast<ushort4*>(owbf)[i - 49152] = o;
    }
}

// ---------------- k_pos prep (fp32, exact): kpos[which][p][d]
__global__ __launch_bounds__(256)
void prep_kpos(const float* __restrict__ pos_y, const float* __restrict__ pos_x,
               const float* __restrict__ W, float* __restrict__ kpos) {
    int p = blockIdx.x;          // 0..40
    int which = blockIdx.y;      // 0=y, 1=x
    __shared__ float pr[128];
    int d = threadIdx.x;         // 0..255
    if (d < 128) pr[d] = which ? pos_x[p * 128 + d] : pos_y[p * 128 + d];
    __syncthreads();
    const float* Wk = W + 256 * 256;  // w_k rows
    int fOff = which ? 128 : 0;
    float acc = 0.f;
    #pragma unroll 8
    for (int f = 0; f < 128; ++f)
        acc += pr[f] * Wk[(size_t)d * 256 + fOff + f];
    kpos[((size_t)which * PP + p) * 256 + d] = acc;
}

// ---------------- MFMA projection: out[m,n] = (sum_k X[m,k]*W[n,k] + b[n])*scale (bf16 out)
// X fp32 split to bf16 hi/lo (2 MFMAs), W bf16 pre-converted (L2-resident).
// Block: 256 thr = 4 waves; BM=64 (16 rows/wave), BN=256 (16 n-tiles), K=256.
__global__ __launch_bounds__(256)
void proj_mfma(const float* __restrict__ X, const unsigned short* __restrict__ Wb,
               const float* __restrict__ bias, float scale,
               unsigned short* __restrict__ out) {
    __shared__ unsigned short st[4][16][264];   // store-staging per wave
    int tid = threadIdx.x, wid = tid >> 6, lane = tid & 63;
    int rgrp = lane & 15, kgrp = lane >> 4;
    int row0 = blockIdx.x * 64 + wid * 16;
    const float* xp = X + (size_t)(row0 + rgrp) * 256 + kgrp * 8;

    f32x4 acc[16];
    #pragma unroll
    for (int i = 0; i < 16; ++i) acc[i] = (f32x4){0.f, 0.f, 0.f, 0.f};

    for (int k0 = 0; k0 < 256; k0 += 32) {
        bf16x8 bfrag[16];
        #pragma unroll
        for (int nt = 0; nt < 16; ++nt) {
            const unsigned short* wp = Wb + (size_t)(nt * 16 + rgrp) * 256 + k0 + kgrp * 8;
            bfrag[nt] = *reinterpret_cast<const bf16x8*>(wp);
        }
        float4 a0 = *reinterpret_cast<const float4*>(xp + k0);
        float4 a1 = *reinterpret_cast<const float4*>(xp + k0 + 4);
        float xf[8] = {a0.x, a0.y, a0.z, a0.w, a1.x, a1.y, a1.z, a1.w};
        union { unsigned short s[8]; bf16x8 v; } hu, lu;
        #pragma unroll
        for (int j = 0; j < 8; ++j) {
            unsigned short h = f2bf(xf[j]);
            hu.s[j] = h;
            lu.s[j] = f2bf(xf[j] - bf2f(h));
        }
        #pragma unroll
        for (int nt = 0; nt < 16; ++nt) {
            acc[nt] = __builtin_amdgcn_mfma_f32_16x16x32_bf16(hu.v, bfrag[nt], acc[nt], 0, 0, 0);
            acc[nt] = __builtin_amdgcn_mfma_f32_16x16x32_bf16(lu.v, bfrag[nt], acc[nt], 0, 0, 0);
        }
    }
    // epilogue: bias+scale, stage bf16 in LDS, vector store
    #pragma unroll
    for (int nt = 0; nt < 16; ++nt) {
        int col = nt * 16 + rgrp;
        float b = bias[col];
        #pragma unroll
        for (int i = 0; i < 4; ++i)
            st[wid][kgrp * 4 + i][col] = f2bf((acc[nt][i] + b) * scale);
    }
    #pragma unroll
    for (int it = 0; it < 8; ++it) {
        int q = it * 64 + lane;          // 0..511: 16 rows x 32 chunks of 8 shorts
        int rr = q >> 5, cc = q & 31;
        u16x8 v = *reinterpret_cast<const u16x8*>(&st[wid][rr][cc * 8]);
        *reinterpret_cast<u16x8*>(&out[(size_t)(row0 + rr) * 256 + cc * 8]) = v;
    }
}

// ---------------- MFMA output projection: out fp32 = ctx(bf16) @ out_w^T + out_b
__global__ __launch_bounds__(256)
void out_mfma(const unsigned short* __restrict__ Xb, const unsigned short* __restrict__ Wb,
              const float* __restrict__ bias, float* __restrict__ out) {
    int tid = threadIdx.x, wid = tid >> 6, lane = tid & 63;
    int rgrp = lane & 15, kgrp = lane >> 4;
    int row0 = blockIdx.x * 64 + wid * 16;
    const unsigned short* xp = Xb + (size_t)(row0 + rgrp) * 256 + kgrp * 8;

    f32x4 acc[16];
    #pragma unroll
    for (int i = 0; i < 16; ++i) acc[i] = (f32x4){0.f, 0.f, 0.f, 0.f};

    for (int k0 = 0; k0 < 256; k0 += 32) {
        bf16x8 afrag = *reinterpret_cast<const bf16x8*>(xp + k0);
        #pragma unroll
        for (int nt = 0; nt < 16; ++nt) {
            const unsigned short* wp = Wb + (size_t)(nt * 16 + rgrp) * 256 + k0 + kgrp * 8;
            bf16x8 bfrag = *reinterpret_cast<const bf16x8*>(wp);
            acc[nt] = __builtin_amdgcn_mfma_f32_16x16x32_bf16(afrag, bfrag, acc[nt], 0, 0, 0);
        }
    }
    #pragma unroll
    for (int nt = 0; nt < 16; ++nt) {
        int col = nt * 16 + rgrp;
        float b = bias[col];
        #pragma unroll
        for (int i = 0; i < 4; ++i)
            out[(size_t)(row0 + kgrp * 4 + i) * 256 + col] = acc[nt][i] + b;
    }
}

// ---------------- fused attention per (b,h) block
__global__ __launch_bounds__(256)
void attn_kernel(const unsigned short* __restrict__ qbuf,
                 const unsigned short* __restrict__ kbuf,
                 const unsigned short* __restrict__ vbuf,
                 const float* __restrict__ kpos,
                 const unsigned char* __restrict__ mask,
                 unsigned short* __restrict__ ctx,
                 int B) {
    __shared__ float Qs[L_Q][DK + 1], Ks[L_Q][DK + 1];
    __shared__ float KP[2][PP][DK + 1];      // kpy,kpx; later V aliases here
    __shared__ float U[2 * L_Q * 42];        // posy|posx, later S[49][50]
    __shared__ int yy[L_Q], xx[L_Q];
    __shared__ unsigned char mb[52];
    float* Vf = &KP[0][0][0];                // V[l*33+d], 1615 floats < 2706

    int b = blockIdx.x, h = blockIdx.y;
    int tid = threadIdx.x;

    if (tid < L_Q) mb[tid] = mask[(size_t)b * L_Q + tid];
    __syncthreads();
    if (tid < L_Q) {
        int r = tid / 7, c = tid % 7;
        int sy = 0, sx = 0;
        for (int rr = 0; rr <= r; ++rr) sy += (mb[rr * 7 + c] == 0);
        for (int cc = 0; cc <= c; ++cc) sx += (mb[r * 7 + cc] == 0);
        yy[tid] = sy; xx[tid] = sx;
    }

    size_t base = (size_t)b * D_MODEL + (size_t)h * DK;
    size_t lstride = (size_t)B * D_MODEL;
    if (tid < 196) {                          // Q,K: 49 rows x 4 chunks of 8
        int l = tid >> 2, c = tid & 3;
        u16x8 qv = *reinterpret_cast<const u16x8*>(qbuf + (size_t)l * lstride + base + c * 8);
        u16x8 kv = *reinterpret_cast<const u16x8*>(kbuf + (size_t)l * lstride + base + c * 8);
        #pragma unroll
        for (int j = 0; j < 8; ++j) {
            Qs[l][c * 8 + j] = bf2f(qv[j]);
            Ks[l][c * 8 + j] = bf2f(kv[j]);
        }
    }
    for (int e = tid; e < PP * 8; e += 256) { // kpos: 41 rows x 8 float4, two tables
        int p = e >> 3, c = e & 7;
        float4 vy = *reinterpret_cast<const float4*>(kpos + (size_t)p * D_MODEL + h * DK + c * 4);
        float4 vx = *reinterpret_cast<const float4*>(kpos + (size_t)(PP + p) * D_MODEL + h * DK + c * 4);
        KP[0][p][c * 4 + 0] = vy.x; KP[0][p][c * 4 + 1] = vy.y;
        KP[0][p][c * 4 + 2] = vy.z; KP[0][p][c * 4 + 3] = vy.w;
        KP[1][p][c * 4 + 0] = vx.x; KP[1][p][c * 4 + 1] = vx.y;
        KP[1][p][c * 4 + 2] = vx.z; KP[1][p][c * 4 + 3] = vx.w;
    }
    __syncthreads();

    // phase1: posy[l][p], posx[l][p] = Q[l] . kpy/kpx[p]
    for (int e = tid; e < 2 * L_Q * PP; e += 256) {
        int which = e >= L_Q * PP;
        int e2 = which ? e - L_Q * PP : e;
        int l = e2 / PP, p = e2 - l * PP;
        float a = 0.f;
        #pragma unroll 8
        for (int d = 0; d < DK; ++d) a += Qs[l][d] * KP[which][p][d];
        U[which * (L_Q * 42) + l * 42 + p] = a;
    }
    __syncthreads();

    // phase2: S = QK^T + gathered pos (to registers); stage V over KP region
    float sreg[10];
    #pragma unroll
    for (int it = 0; it < 10; ++it) {
        int e = tid + it * 256;
        if (e < L_Q * L_Q) {
            int l = e / L_Q, s = e - l * L_Q;
            float a = 0.f;
            #pragma unroll 8
            for (int d = 0; d < DK; ++d) a += Qs[l][d] * Ks[s][d];
            int iy = yy[l] - yy[s] + POS_OFF;
            int ix = xx[l] - xx[s] + POS_OFF;
            a += U[l * 42 + iy] + U[L_Q * 42 + l * 42 + ix];
            sreg[it] = mb[s] ? -1e30f : a;
        }
    }
    if (tid < 196) {
        int l = tid >> 2, c = tid & 3;
        u16x8 vv = *reinterpret_cast<const u16x8*>(vbuf + (size_t)l * lstride + base + c * 8);
        #pragma unroll
        for (int j = 0; j < 8; ++j) Vf[l * 33 + c * 8 + j] = bf2f(vv[j]);
    }
    __syncthreads();

    // phase3: write S[49][50] over pos region
    #pragma unroll
    for (int it = 0; it < 10; ++it) {
        int e = tid + it * 256;
        if (e < L_Q * L_Q) {
            int l = e / L_Q, s = e - l * L_Q;
            U[l * 50 + s] = sreg[it];
        }
    }
    __syncthreads();

    // softmax: 4 threads per row, shfl_xor group reduce
    if (tid < 196) {
        int l = tid >> 2, q = tid & 3;
        float m = -1e30f;
        for (int s = q; s < L_Q; s += 4) m = fmaxf(m, U[l * 50 + s]);
        m = fmaxf(m, __shfl_xor(m, 1));
        m = fmaxf(m, __shfl_xor(m, 2));
        float sum = 0.f;
        for (int s = q; s < L_Q; s += 4) {
            float ex = __expf(U[l * 50 + s] - m);
            U[l * 50 + s] = ex; sum += ex;
        }
        sum += __shfl_xor(sum, 1);
        sum += __shfl_xor(sum, 2);
        float inv = 1.f / sum;
        for (int s = q; s < L_Q; s += 4) U[l * 50 + s] *= inv;
    }
    __syncthreads();

    // PV
    for (int e = tid; e < L_Q * DK; e += 256) {
        int l = e >> 5, d = e & 31;
        float a = 0.f;
        #pragma unroll 7
        for (int s = 0; s < L_Q; ++s) a += U[l * 50 + s] * Vf[s * 33 + d];
        ctx[(size_t)l * lstride + base + d] = f2bf(a);
    }
}

extern "C" void kernel_launch(void* const* d_in, const int* in_sizes, int n_in,
                              void* d_out, int out_size, void* d_ws, size_t ws_size,
                              hipStream_t stream) {
    const float* query = (const float*)d_in[0];
    const float* key   = (const float*)d_in[1];
    const float* value = (const float*)d_in[2];
    const unsigned char* maskp = (const unsigned char*)d_in[3];
    const float* W     = (const float*)d_in[4];   // (768,256)
    const float* bias  = (const float*)d_in[5];   // (768,)
    const float* out_w = (const float*)d_in[6];   // (256,256)
    const float* out_b = (const float*)d_in[7];   // (256,)
    const float* pos_x = (const float*)d_in[8];   // (41,128)
    const float* pos_y = (const float*)d_in[9];   // (41,128)
    float* out = (float*)d_out;

    int B = in_sizes[0] / (L_Q * D_MODEL);        // 2048
    int M = L_Q * B;                              // 100352 (divisible by 64)

    size_t nqkv = (size_t)M * D_MODEL;
    unsigned short* qb = (unsigned short*)d_ws;
    unsigned short* kb = qb + nqkv;
    unsigned short* vb = kb + nqkv;
    float* kpos = (float*)(vb + nqkv);            // [2][41][256] f32
    unsigned short* wbf = (unsigned short*)(kpos + 2 * PP * D_MODEL);  // 768x256 bf16
    unsigned short* owbf = wbf + 768 * 256;       // 256x256 bf16

    const float scaling = 0.17677669529663687f;   // 1/sqrt(32)

    convert_w<<<256, 256, 0, stream>>>(W, out_w, wbf, owbf);
    prep_kpos<<<dim3(PP, 2), 256, 0, stream>>>(pos_y, pos_x, W, kpos);

    int gblocks = M / 64;                         // 1568
    proj_mfma<<<gblocks, 256, 0, stream>>>(query, wbf,             bias,       scaling, qb);
    proj_mfma<<<gblocks, 256, 0, stream>>>(key,   wbf + 256 * 256, bias + 256, 1.0f,    kb);
    proj_mfma<<<gblocks, 256, 0, stream>>>(value, wbf + 512 * 256, bias + 512, 1.0f,    vb);

    attn_kernel<<<dim3(B, NHEAD), 256, 0, stream>>>(qb, kb, vb, kpos, maskp, qb, B);

    out_mfma<<<gblocks, 256, 0, stream>>>(qb, owbf, out_b, out);
}

// Round 3
// 595.034 us; speedup vs baseline: 2.5505x; 1.9992x over previous
//
#include <hip/hip_runtime.h>
#include <hip/hip_bf16.h>

#define L_Q 49
#define D_MODEL 256
#define NHEAD 8
#define DK 32
#define PP 41
#define POS_OFF 20

typedef __attribute__((ext_vector_type(8))) __bf16 bf16x8;
typedef __attribute__((ext_vector_type(4))) float f32x4;
typedef __attribute__((ext_vector_type(8))) unsigned short u16x8;

__device__ __forceinline__ float bf2f(unsigned short u) {
    return __uint_as_float(((unsigned)u) << 16);
}
__device__ __forceinline__ unsigned short f2bf(float f) {
    unsigned u = __float_as_uint(f);
    return (unsigned short)((u + 0x7FFF + ((u >> 16) & 1)) >> 16);
}

// ---------------- one-time W conversion to bf16: W(768x256) then out_w(256x256)
__global__ __launch_bounds__(256)
void convert_w(const float* __restrict__ W, const float* __restrict__ out_w,
               unsigned short* __restrict__ wbf, unsigned short* __restrict__ owbf) {
    int i = blockIdx.x * 256 + threadIdx.x;   // 65536 float4 total
    if (i < 49152) {
        float4 v = reinterpret_cast<const float4*>(W)[i];
        ushort4 o = { f2bf(v.x), f2bf(v.y), f2bf(v.z), f2bf(v.w) };
        reinterpret_cast<ushort4*>(wbf)[i] = o;
    } else {
        float4 v = reinterpret_cast<const float4*>(out_w)[i - 49152];
        ushort4 o = { f2bf(v.x), f2bf(v.y), f2bf(v.z), f2bf(v.w) };
        reinterpret_cast<ushort4*>(owbf)[i - 49152] = o;
    }
}

// ---------------- k_pos prep (f32 accumulate, bf16 store): kpb[which][p][d]
__global__ __launch_bounds__(256)
void prep_kpos(const float* __restrict__ pos_y, const float* __restrict__ pos_x,
               const float* __restrict__ W, unsigned short* __restrict__ kpb) {
    int p = blockIdx.x;          // 0..40
    int which = blockIdx.y;      // 0=y, 1=x
    __shared__ float pr[128];
    int d = threadIdx.x;         // 0..255
    if (d < 128) pr[d] = which ? pos_x[p * 128 + d] : pos_y[p * 128 + d];
    __syncthreads();
    const float* Wk = W + 256 * 256;  // w_k rows
    int fOff = which ? 128 : 0;
    float acc = 0.f;
    #pragma unroll 8
    for (int f = 0; f < 128; ++f)
        acc += pr[f] * Wk[(size_t)d * 256 + fOff + f];
    kpb[((size_t)which * PP + p) * 256 + d] = f2bf(acc);
}

// ---------------- MFMA projection: out[m,n] = (sum_k X[m,k]*W[n,k] + b[n])*scale (bf16 out)
__global__ __launch_bounds__(256)
void proj_mfma(const float* __restrict__ X, const unsigned short* __restrict__ Wb,
               const float* __restrict__ bias, float scale,
               unsigned short* __restrict__ out) {
    __shared__ unsigned short st[4][16][264];   // store-staging per wave
    int tid = threadIdx.x, wid = tid >> 6, lane = tid & 63;
    int rgrp = lane & 15, kgrp = lane >> 4;
    int row0 = blockIdx.x * 64 + wid * 16;
    const float* xp = X + (size_t)(row0 + rgrp) * 256 + kgrp * 8;

    f32x4 acc[16];
    #pragma unroll
    for (int i = 0; i < 16; ++i) acc[i] = (f32x4){0.f, 0.f, 0.f, 0.f};

    for (int k0 = 0; k0 < 256; k0 += 32) {
        bf16x8 bfrag[16];
        #pragma unroll
        for (int nt = 0; nt < 16; ++nt) {
            const unsigned short* wp = Wb + (size_t)(nt * 16 + rgrp) * 256 + k0 + kgrp * 8;
            bfrag[nt] = *reinterpret_cast<const bf16x8*>(wp);
        }
        float4 a0 = *reinterpret_cast<const float4*>(xp + k0);
        float4 a1 = *reinterpret_cast<const float4*>(xp + k0 + 4);
        float xf[8] = {a0.x, a0.y, a0.z, a0.w, a1.x, a1.y, a1.z, a1.w};
        union { unsigned short s[8]; bf16x8 v; } hu, lu;
        #pragma unroll
        for (int j = 0; j < 8; ++j) {
            unsigned short h = f2bf(xf[j]);
            hu.s[j] = h;
            lu.s[j] = f2bf(xf[j] - bf2f(h));
        }
        #pragma unroll
        for (int nt = 0; nt < 16; ++nt) {
            acc[nt] = __builtin_amdgcn_mfma_f32_16x16x32_bf16(hu.v, bfrag[nt], acc[nt], 0, 0, 0);
            acc[nt] = __builtin_amdgcn_mfma_f32_16x16x32_bf16(lu.v, bfrag[nt], acc[nt], 0, 0, 0);
        }
    }
    #pragma unroll
    for (int nt = 0; nt < 16; ++nt) {
        int col = nt * 16 + rgrp;
        float b = bias[col];
        #pragma unroll
        for (int i = 0; i < 4; ++i)
            st[wid][kgrp * 4 + i][col] = f2bf((acc[nt][i] + b) * scale);
    }
    #pragma unroll
    for (int it = 0; it < 8; ++it) {
        int q = it * 64 + lane;          // 16 rows x 32 chunks of 8 shorts
        int rr = q >> 5, cc = q & 31;
        u16x8 v = *reinterpret_cast<const u16x8*>(&st[wid][rr][cc * 8]);
        *reinterpret_cast<u16x8*>(&out[(size_t)(row0 + rr) * 256 + cc * 8]) = v;
    }
}

// ---------------- MFMA output projection: out fp32 = ctx(bf16) @ out_w^T + out_b
__global__ __launch_bounds__(256)
void out_mfma(const unsigned short* __restrict__ Xb, const unsigned short* __restrict__ Wb,
              const float* __restrict__ bias, float* __restrict__ out) {
    int tid = threadIdx.x, wid = tid >> 6, lane = tid & 63;
    int rgrp = lane & 15, kgrp = lane >> 4;
    int row0 = blockIdx.x * 64 + wid * 16;
    const unsigned short* xp = Xb + (size_t)(row0 + rgrp) * 256 + kgrp * 8;

    f32x4 acc[16];
    #pragma unroll
    for (int i = 0; i < 16; ++i) acc[i] = (f32x4){0.f, 0.f, 0.f, 0.f};

    for (int k0 = 0; k0 < 256; k0 += 32) {
        bf16x8 afrag = *reinterpret_cast<const bf16x8*>(xp + k0);
        #pragma unroll
        for (int nt = 0; nt < 16; ++nt) {
            const unsigned short* wp = Wb + (size_t)(nt * 16 + rgrp) * 256 + k0 + kgrp * 8;
            bf16x8 bfrag = *reinterpret_cast<const bf16x8*>(wp);
            acc[nt] = __builtin_amdgcn_mfma_f32_16x16x32_bf16(afrag, bfrag, acc[nt], 0, 0, 0);
        }
    }
    #pragma unroll
    for (int nt = 0; nt < 16; ++nt) {
        int col = nt * 16 + rgrp;
        float b = bias[col];
        #pragma unroll
        for (int i = 0; i < 4; ++i)
            out[(size_t)(row0 + kgrp * 4 + i) * 256 + col] = acc[nt][i] + b;
    }
}

// ---------------- MFMA fused attention: one (b,h) per 4-wave block
// Wave w owns output rows 16w..16w+15. Only pos rows p in [13,27] are ever
// gathered (cumsum diffs are in [-7,7]), so one 16-wide tile per pos table.
__global__ __launch_bounds__(256)
void attn_mfma(const unsigned short* __restrict__ qbuf,
               const unsigned short* __restrict__ kbuf,
               const unsigned short* __restrict__ vbuf,
               const unsigned short* __restrict__ kpb,
               const unsigned char* __restrict__ mask,
               unsigned short* __restrict__ ctx,
               int B) {
    __shared__ unsigned short Kp[96][40];      // K'(rows: 0..63 K, 64..79 kpy, 80..95 kpx)
    __shared__ unsigned short Pt[64][72];      // P bf16, rows l, cols s (49..63 zero)
    __shared__ unsigned short Vt[32][72];      // V^T: [d][s], cols 49..63 zeroed
    __shared__ unsigned short postab[49][40];  // [l][0..15]=posy(p=13+c), [l][20..35]=posx
    __shared__ int yy[L_Q], xx[L_Q];
    __shared__ unsigned char mb[52];

    int b = blockIdx.x, h = blockIdx.y;
    int tid = threadIdx.x, wid = tid >> 6, lane = tid & 63;
    int rgrp = lane & 15, kgrp = lane >> 4;
    size_t lstride = (size_t)B * D_MODEL;
    size_t base = (size_t)b * D_MODEL + (size_t)h * DK;

    // ---- phase 0: cooperative staging
    if (tid < L_Q) mb[tid] = mask[(size_t)b * L_Q + tid];
    if (tid < 196) {                      // V: l = tid>>2, 8 cols each -> transpose
        int l = tid >> 2, c = tid & 3;
        u16x8 vv = *reinterpret_cast<const u16x8*>(vbuf + (size_t)l * lstride + base + c * 8);
        #pragma unroll
        for (int j = 0; j < 8; ++j) Vt[c * 8 + j][l] = vv[j];
    }
    for (int e = tid; e < 512; e += 256) { // zero Vt cols 49..63
        int d = e >> 4, s2 = 48 + (e & 15);
        if (s2 > 48) Vt[d][s2] = 0;
    }
    for (int t = tid; t < 384; t += 256) { // K' staging: 96 rows x 4 chunks
        int r = t >> 2, kc = t & 3;
        const unsigned short* src;
        if (r < 64) {
            int kr = min(r, 48);
            src = kbuf + (size_t)kr * lstride + base + kc * 8;
        } else if (r < 80) {
            int p = r - 64 + 13;
            src = kpb + (size_t)p * D_MODEL + h * DK + kc * 8;
        } else {
            int p = r - 80 + 13;
            src = kpb + (size_t)(PP + p) * D_MODEL + h * DK + kc * 8;
        }
        *reinterpret_cast<u16x8*>(&Kp[r][kc * 8]) = *reinterpret_cast<const u16x8*>(src);
    }
    __syncthreads();
    if (tid < L_Q) {
        int r = tid / 7, c = tid % 7;
        int sy = 0, sx = 0;
        for (int rr = 0; rr <= r; ++rr) sy += (mb[rr * 7 + c] == 0);
        for (int cc = 0; cc <= c; ++cc) sx += (mb[r * 7 + cc] == 0);
        yy[tid] = sy; xx[tid] = sx;
    }
    __syncthreads();

    // ---- phase 1: S_full = Q . K'^T  (6 MFMAs, wave w = row tile w)
    int qrow = min(16 * wid + rgrp, 48);
    bf16x8 qfrag = *reinterpret_cast<const bf16x8*>(qbuf + (size_t)qrow * lstride + base + kgrp * 8);
    f32x4 acc[6];
    #pragma unroll
    for (int t = 0; t < 6; ++t) {
        bf16x8 bfrag = *reinterpret_cast<const bf16x8*>(&Kp[t * 16 + rgrp][kgrp * 8]);
        acc[t] = __builtin_amdgcn_mfma_f32_16x16x32_bf16(qfrag, bfrag,
                    (f32x4){0.f, 0.f, 0.f, 0.f}, 0, 0, 0);
    }

    // ---- phase 2: spill pos tiles (own rows only), assemble, softmax, write P
    #pragma unroll
    for (int i = 0; i < 4; ++i) {
        int l = 16 * wid + kgrp * 4 + i;
        if (l <= 48) {
            postab[l][rgrp]      = f2bf(acc[4][i]);
            postab[l][20 + rgrp] = f2bf(acc[5][i]);
        }
    }
    asm volatile("s_waitcnt lgkmcnt(0)" ::: "memory");

    #pragma unroll
    for (int i = 0; i < 4; ++i) {
        int l = 16 * wid + kgrp * 4 + i;
        int lc = min(l, 48);
        int yyl = yy[lc], xxl = xx[lc];
        float v[4];
        #pragma unroll
        for (int ct = 0; ct < 4; ++ct) {
            int s = ct * 16 + rgrp;
            int sc = min(s, 48);
            int iy = yyl - yy[sc] + (POS_OFF - 13);   // 0..14
            int ix = xxl - xx[sc] + (POS_OFF - 13);
            float val = acc[ct][i] + bf2f(postab[lc][iy]) + bf2f(postab[lc][20 + ix]);
            v[ct] = (s >= L_Q || mb[sc]) ? -1e30f : val;
        }
        float m = fmaxf(fmaxf(v[0], v[1]), fmaxf(v[2], v[3]));
        m = fmaxf(m, __shfl_xor(m, 1));
        m = fmaxf(m, __shfl_xor(m, 2));
        m = fmaxf(m, __shfl_xor(m, 4));
        m = fmaxf(m, __shfl_xor(m, 8));
        float ssum = 0.f, ex[4];
        #pragma unroll
        for (int ct = 0; ct < 4; ++ct) { ex[ct] = __expf(v[ct] - m); ssum += ex[ct]; }
        ssum += __shfl_xor(ssum, 1);
        ssum += __shfl_xor(ssum, 2);
        ssum += __shfl_xor(ssum, 4);
        ssum += __shfl_xor(ssum, 8);
        float is = 1.f / ssum;
        #pragma unroll
        for (int ct = 0; ct < 4; ++ct)
            Pt[l & 63][ct * 16 + rgrp] = f2bf(ex[ct] * is);
    }
    asm volatile("s_waitcnt lgkmcnt(0)" ::: "memory");

    // ---- phase 3: PV (4 MFMAs) + store
    f32x4 oacc[2];
    oacc[0] = (f32x4){0.f, 0.f, 0.f, 0.f};
    oacc[1] = (f32x4){0.f, 0.f, 0.f, 0.f};
    #pragma unroll
    for (int kc = 0; kc < 2; ++kc) {
        bf16x8 pa = *reinterpret_cast<const bf16x8*>(&Pt[16 * wid + rgrp][kc * 32 + kgrp * 8]);
        #pragma unroll
        for (int dt = 0; dt < 2; ++dt) {
            bf16x8 vb = *reinterpret_cast<const bf16x8*>(&Vt[dt * 16 + rgrp][kc * 32 + kgrp * 8]);
            oacc[dt] = __builtin_amdgcn_mfma_f32_16x16x32_bf16(pa, vb, oacc[dt], 0, 0, 0);
        }
    }
    #pragma unroll
    for (int dt = 0; dt < 2; ++dt)
        #pragma unroll
        for (int i = 0; i < 4; ++i) {
            int l = 16 * wid + kgrp * 4 + i;
            if (l <= 48)
                ctx[(size_t)l * lstride + base + dt * 16 + rgrp] = f2bf(oacc[dt][i]);
        }
}

extern "C" void kernel_launch(void* const* d_in, const int* in_sizes, int n_in,
                              void* d_out, int out_size, void* d_ws, size_t ws_size,
                              hipStream_t stream) {
    const float* query = (const float*)d_in[0];
    const float* key   = (const float*)d_in[1];
    const float* value = (const float*)d_in[2];
    const unsigned char* maskp = (const unsigned char*)d_in[3];
    const float* W     = (const float*)d_in[4];   // (768,256)
    const float* bias  = (const float*)d_in[5];   // (768,)
    const float* out_w = (const float*)d_in[6];   // (256,256)
    const float* out_b = (const float*)d_in[7];   // (256,)
    const float* pos_x = (const float*)d_in[8];   // (41,128)
    const float* pos_y = (const float*)d_in[9];   // (41,128)
    float* out = (float*)d_out;

    int B = in_sizes[0] / (L_Q * D_MODEL);        // 2048
    int M = L_Q * B;                              // 100352 (divisible by 64)

    size_t nqkv = (size_t)M * D_MODEL;
    unsigned short* qb = (unsigned short*)d_ws;
    unsigned short* kb = qb + nqkv;
    unsigned short* vb = kb + nqkv;
    unsigned short* kpb = vb + nqkv;              // [2][41][256] bf16
    unsigned short* wbf = kpb + 2 * PP * D_MODEL; // 768x256 bf16
    unsigned short* owbf = wbf + 768 * 256;       // 256x256 bf16

    const float scaling = 0.17677669529663687f;   // 1/sqrt(32)

    convert_w<<<256, 256, 0, stream>>>(W, out_w, wbf, owbf);
    prep_kpos<<<dim3(PP, 2), 256, 0, stream>>>(pos_y, pos_x, W, kpb);

    int gblocks = M / 64;                         // 1568
    proj_mfma<<<gblocks, 256, 0, stream>>>(query, wbf,             bias,       scaling, qb);
    proj_mfma<<<gblocks, 256, 0, stream>>>(key,   wbf + 256 * 256, bias + 256, 1.0f,    kb);
    proj_mfma<<<gblocks, 256, 0, stream>>>(value, wbf + 512 * 256, bias + 512, 1.0f,    vb);

    attn_mfma<<<dim3(B, NHEAD), 256, 0, stream>>>(qb, kb, vb, kpb, maskp, qb, B);

    out_mfma<<<gblocks, 256, 0, stream>>>(qb, owbf, out_b, out);
}

// Round 4
// 287.090 us; speedup vs baseline: 5.2863x; 2.0726x over previous
//
#include <hip/hip_runtime.h>
#include <hip/hip_bf16.h>

#define L_Q 49
#define D_MODEL 256
#define NHEAD 8
#define DK 32
#define PP 41
#define POS_OFF 20

typedef __attribute__((ext_vector_type(8))) __bf16 bf16x8;
typedef __attribute__((ext_vector_type(4))) float f32x4;
typedef __attribute__((ext_vector_type(8))) unsigned short u16x8;

__device__ __forceinline__ float bf2f(unsigned short u) {
    return __uint_as_float(((unsigned)u) << 16);
}
__device__ __forceinline__ unsigned short f2bf(float f) {
    unsigned u = __float_as_uint(f);
    return (unsigned short)((u + 0x7FFF + ((u >> 16) & 1)) >> 16);
}

// ---------------- one-time W conversion to bf16 (q-rows pre-scaled by `scaling`)
__global__ __launch_bounds__(256)
void convert_w(const float* __restrict__ W, const float* __restrict__ out_w,
               float scaling,
               unsigned short* __restrict__ wbf, unsigned short* __restrict__ owbf) {
    int i = blockIdx.x * 256 + threadIdx.x;   // 65536 float4 total
    if (i < 49152) {
        int row = i >> 6;                      // 64 float4 per 256-wide row
        float sc = (row < 256) ? scaling : 1.0f;
        float4 v = reinterpret_cast<const float4*>(W)[i];
        ushort4 o = { f2bf(v.x * sc), f2bf(v.y * sc), f2bf(v.z * sc), f2bf(v.w * sc) };
        reinterpret_cast<ushort4*>(wbf)[i] = o;
    } else {
        float4 v = reinterpret_cast<const float4*>(out_w)[i - 49152];
        ushort4 o = { f2bf(v.x), f2bf(v.y), f2bf(v.z), f2bf(v.w) };
        reinterpret_cast<ushort4*>(owbf)[i - 49152] = o;
    }
}

// ---------------- k_pos prep (f32 accumulate, bf16 store): kpb[which][p][d]
__global__ __launch_bounds__(256)
void prep_kpos(const float* __restrict__ pos_y, const float* __restrict__ pos_x,
               const float* __restrict__ W, unsigned short* __restrict__ kpb) {
    int p = blockIdx.x;          // 0..40
    int which = blockIdx.y;      // 0=y, 1=x
    __shared__ float pr[128];
    int d = threadIdx.x;         // 0..255
    if (d < 128) pr[d] = which ? pos_x[p * 128 + d] : pos_y[p * 128 + d];
    __syncthreads();
    const float* Wk = W + 256 * 256;  // w_k rows
    int fOff = which ? 128 : 0;
    float acc = 0.f;
    #pragma unroll 8
    for (int f = 0; f < 128; ++f)
        acc += pr[f] * Wk[(size_t)d * 256 + fOff + f];
    kpb[((size_t)which * PP + p) * 256 + d] = f2bf(acc);
}

// ---------------- fused 3-way projection, W-in-LDS (swizzled), MFMA
// grid = (M/128, 3); 512 threads = 8 waves; wave w owns rows w*16..w*16+15.
__global__ __launch_bounds__(512)
void proj_mfma(const float* __restrict__ Xq, const float* __restrict__ Xk,
               const float* __restrict__ Xv,
               const unsigned short* __restrict__ Wb,   // 768x256 bf16, q-rows pre-scaled
               const float* __restrict__ bias, float scaling,
               unsigned short* __restrict__ outq, unsigned short* __restrict__ outk,
               unsigned short* __restrict__ outv) {
    __shared__ unsigned short Wl[65536];   // 128 KB, swizzled layout
    __shared__ float Lb[256];
    int which = blockIdx.y;
    const float* X = (which == 0) ? Xq : ((which == 1) ? Xk : Xv);
    unsigned short* out = (which == 0) ? outq : ((which == 1) ? outk : outv);
    const unsigned short* wsrc = Wb + (size_t)which * 65536;

    int tid = threadIdx.x, wid = tid >> 6, lane = tid & 63;
    int rgrp = lane & 15, kgrp = lane >> 4;

    // stage W: linear LDS dest, inverse-swizzled global source (rule #21)
    #pragma unroll
    for (int it = 0; it < 16; ++it) {
        int c = wid + it * 8;                 // chunk 0..127 (1 KB each)
        unsigned dst = (unsigned)c * 1024 + (unsigned)lane * 16;
        unsigned n = dst >> 9;                // W row held at this LDS slot
        unsigned gs = dst ^ ((n & 7) << 4);
        __builtin_amdgcn_global_load_lds((const char*)wsrc + gs,
                                         (char*)Wl + (size_t)c * 1024, 16, 0, 0);
    }
    if (tid < 256) Lb[tid] = bias[which * 256 + tid] * ((which == 0) ? scaling : 1.0f);

    size_t xrow = (size_t)blockIdx.x * 128 + wid * 16 + rgrp;
    const float* xp = X + xrow * 256 + kgrp * 8;
    float4 pa0 = *reinterpret_cast<const float4*>(xp);
    float4 pa1 = *reinterpret_cast<const float4*>(xp + 4);
    __syncthreads();                          // drains vmcnt (global_load_lds + X prefetch)

    f32x4 acc[16];
    #pragma unroll
    for (int i = 0; i < 16; ++i) acc[i] = (f32x4){0.f, 0.f, 0.f, 0.f};

    unsigned lbase = ((unsigned)rgrp * 512 + (unsigned)kgrp * 16) ^ ((rgrp & 7) << 4);

    #pragma unroll
    for (int kk = 0; kk < 8; ++kk) {
        float4 a0 = pa0, a1 = pa1;
        if (kk < 7) {
            pa0 = *reinterpret_cast<const float4*>(xp + (kk + 1) * 32);
            pa1 = *reinterpret_cast<const float4*>(xp + (kk + 1) * 32 + 4);
        }
        union { unsigned short s[8]; bf16x8 v; } xu;
        xu.s[0] = f2bf(a0.x); xu.s[1] = f2bf(a0.y); xu.s[2] = f2bf(a0.z); xu.s[3] = f2bf(a0.w);
        xu.s[4] = f2bf(a1.x); xu.s[5] = f2bf(a1.y); xu.s[6] = f2bf(a1.z); xu.s[7] = f2bf(a1.w);
        unsigned kb = lbase ^ (unsigned)(kk * 64);   // kk*64 bytes, XOR-safe (bit6+)
        #pragma unroll
        for (int nt = 0; nt < 16; ++nt) {
            bf16x8 wf = *reinterpret_cast<const bf16x8*>((const char*)Wl + kb + nt * 8192);
            acc[nt] = __builtin_amdgcn_mfma_f32_16x16x32_bf16(wf, xu.v, acc[nt], 0, 0, 0);
        }
    }

    // epilogue: lane holds col m=rgrp(row xrow), rows n = nt*16+kgrp*4+i
    #pragma unroll
    for (int nt = 0; nt < 16; ++nt) {
        float4 bv = *reinterpret_cast<const float4*>(&Lb[nt * 16 + kgrp * 4]);
        ushort4 pk;
        pk.x = f2bf(acc[nt][0] + bv.x);
        pk.y = f2bf(acc[nt][1] + bv.y);
        pk.z = f2bf(acc[nt][2] + bv.z);
        pk.w = f2bf(acc[nt][3] + bv.w);
        *reinterpret_cast<ushort4*>(&out[xrow * 256 + nt * 16 + kgrp * 4]) = pk;
    }
}

// ---------------- output projection, same skeleton (bf16 A, fp32 out)
__global__ __launch_bounds__(512)
void out_mfma(const unsigned short* __restrict__ Xb, const unsigned short* __restrict__ Wb,
              const float* __restrict__ bias, float* __restrict__ out) {
    __shared__ unsigned short Wl[65536];   // 128 KB, swizzled
    __shared__ float Lb[256];
    int tid = threadIdx.x, wid = tid >> 6, lane = tid & 63;
    int rgrp = lane & 15, kgrp = lane >> 4;

    #pragma unroll
    for (int it = 0; it < 16; ++it) {
        int c = wid + it * 8;
        unsigned dst = (unsigned)c * 1024 + (unsigned)lane * 16;
        unsigned n = dst >> 9;
        unsigned gs = dst ^ ((n & 7) << 4);
        __builtin_amdgcn_global_load_lds((const char*)Wb + gs,
                                         (char*)Wl + (size_t)c * 1024, 16, 0, 0);
    }
    if (tid < 256) Lb[tid] = bias[tid];

    size_t xrow = (size_t)blockIdx.x * 128 + wid * 16 + rgrp;
    const unsigned short* xp = Xb + xrow * 256 + kgrp * 8;
    bf16x8 pa = *reinterpret_cast<const bf16x8*>(xp);
    __syncthreads();

    f32x4 acc[16];
    #pragma unroll
    for (int i = 0; i < 16; ++i) acc[i] = (f32x4){0.f, 0.f, 0.f, 0.f};

    unsigned lbase = ((unsigned)rgrp * 512 + (unsigned)kgrp * 16) ^ ((rgrp & 7) << 4);

    #pragma unroll
    for (int kk = 0; kk < 8; ++kk) {
        bf16x8 af = pa;
        if (kk < 7) pa = *reinterpret_cast<const bf16x8*>(xp + (kk + 1) * 32);
        unsigned kb = lbase ^ (unsigned)(kk * 64);
        #pragma unroll
        for (int nt = 0; nt < 16; ++nt) {
            bf16x8 wf = *reinterpret_cast<const bf16x8*>((const char*)Wl + kb + nt * 8192);
            acc[nt] = __builtin_amdgcn_mfma_f32_16x16x32_bf16(wf, af, acc[nt], 0, 0, 0);
        }
    }

    #pragma unroll
    for (int nt = 0; nt < 16; ++nt) {
        float4 bv = *reinterpret_cast<const float4*>(&Lb[nt * 16 + kgrp * 4]);
        float4 o;
        o.x = acc[nt][0] + bv.x;
        o.y = acc[nt][1] + bv.y;
        o.z = acc[nt][2] + bv.z;
        o.w = acc[nt][3] + bv.w;
        *reinterpret_cast<float4*>(&out[xrow * 256 + nt * 16 + kgrp * 4]) = o;
    }
}

// ---------------- MFMA fused attention: one (b,h) per 4-wave block (unchanged)
__global__ __launch_bounds__(256)
void attn_mfma(const unsigned short* __restrict__ qbuf,
               const unsigned short* __restrict__ kbuf,
               const unsigned short* __restrict__ vbuf,
               const unsigned short* __restrict__ kpb,
               const unsigned char* __restrict__ mask,
               unsigned short* __restrict__ ctx,
               int B) {
    __shared__ unsigned short Kp[96][40];      // K'(rows: 0..63 K, 64..79 kpy, 80..95 kpx)
    __shared__ unsigned short Pt[64][72];      // P bf16, rows l, cols s (49..63 zero)
    __shared__ unsigned short Vt[32][72];      // V^T: [d][s], cols 49..63 zeroed
    __shared__ unsigned short postab[49][40];  // [l][0..15]=posy(p=13+c), [l][20..35]=posx
    __shared__ int yy[L_Q], xx[L_Q];
    __shared__ unsigned char mb[52];

    int b = blockIdx.x, h = blockIdx.y;
    int tid = threadIdx.x, wid = tid >> 6, lane = tid & 63;
    int rgrp = lane & 15, kgrp = lane >> 4;
    size_t lstride = (size_t)B * D_MODEL;
    size_t base = (size_t)b * D_MODEL + (size_t)h * DK;

    // ---- phase 0: cooperative staging
    if (tid < L_Q) mb[tid] = mask[(size_t)b * L_Q + tid];
    if (tid < 196) {                      // V: l = tid>>2, 8 cols each -> transpose
        int l = tid >> 2, c = tid & 3;
        u16x8 vv = *reinterpret_cast<const u16x8*>(vbuf + (size_t)l * lstride + base + c * 8);
        #pragma unroll
        for (int j = 0; j < 8; ++j) Vt[c * 8 + j][l] = vv[j];
    }
    for (int e = tid; e < 512; e += 256) { // zero Vt cols 49..63
        int d = e >> 4, s2 = 48 + (e & 15);
        if (s2 > 48) Vt[d][s2] = 0;
    }
    for (int t = tid; t < 384; t += 256) { // K' staging: 96 rows x 4 chunks
        int r = t >> 2, kc = t & 3;
        const unsigned short* src;
        if (r < 64) {
            int kr = min(r, 48);
            src = kbuf + (size_t)kr * lstride + base + kc * 8;
        } else if (r < 80) {
            int p = r - 64 + 13;
            src = kpb + (size_t)p * D_MODEL + h * DK + kc * 8;
        } else {
            int p = r - 80 + 13;
            src = kpb + (size_t)(PP + p) * D_MODEL + h * DK + kc * 8;
        }
        *reinterpret_cast<u16x8*>(&Kp[r][kc * 8]) = *reinterpret_cast<const u16x8*>(src);
    }
    __syncthreads();
    if (tid < L_Q) {
        int r = tid / 7, c = tid % 7;
        int sy = 0, sx = 0;
        for (int rr = 0; rr <= r; ++rr) sy += (mb[rr * 7 + c] == 0);
        for (int cc = 0; cc <= c; ++cc) sx += (mb[r * 7 + cc] == 0);
        yy[tid] = sy; xx[tid] = sx;
    }
    __syncthreads();

    // ---- phase 1: S_full = Q . K'^T  (6 MFMAs, wave w = row tile w)
    int qrow = min(16 * wid + rgrp, 48);
    bf16x8 qfrag = *reinterpret_cast<const bf16x8*>(qbuf + (size_t)qrow * lstride + base + kgrp * 8);
    f32x4 acc[6];
    #pragma unroll
    for (int t = 0; t < 6; ++t) {
        bf16x8 bfrag = *reinterpret_cast<const bf16x8*>(&Kp[t * 16 + rgrp][kgrp * 8]);
        acc[t] = __builtin_amdgcn_mfma_f32_16x16x32_bf16(qfrag, bfrag,
                    (f32x4){0.f, 0.f, 0.f, 0.f}, 0, 0, 0);
    }

    // ---- phase 2: spill pos tiles (own rows only), assemble, softmax, write P
    #pragma unroll
    for (int i = 0; i < 4; ++i) {
        int l = 16 * wid + kgrp * 4 + i;
        if (l <= 48) {
            postab[l][rgrp]      = f2bf(acc[4][i]);
            postab[l][20 + rgrp] = f2bf(acc[5][i]);
        }
    }
    asm volatile("s_waitcnt lgkmcnt(0)" ::: "memory");

    #pragma unroll
    for (int i = 0; i < 4; ++i) {
        int l = 16 * wid + kgrp * 4 + i;
        int lc = min(l, 48);
        int yyl = yy[lc], xxl = xx[lc];
        float v[4];
        #pragma unroll
        for (int ct = 0; ct < 4; ++ct) {
            int s = ct * 16 + rgrp;
            int sc = min(s, 48);
            int iy = yyl - yy[sc] + (POS_OFF - 13);   // 0..14
            int ix = xxl - xx[sc] + (POS_OFF - 13);
            float val = acc[ct][i] + bf2f(postab[lc][iy]) + bf2f(postab[lc][20 + ix]);
            v[ct] = (s >= L_Q || mb[sc]) ? -1e30f : val;
        }
        float m = fmaxf(fmaxf(v[0], v[1]), fmaxf(v[2], v[3]));
        m = fmaxf(m, __shfl_xor(m, 1));
        m = fmaxf(m, __shfl_xor(m, 2));
        m = fmaxf(m, __shfl_xor(m, 4));
        m = fmaxf(m, __shfl_xor(m, 8));
        float ssum = 0.f, ex[4];
        #pragma unroll
        for (int ct = 0; ct < 4; ++ct) { ex[ct] = __expf(v[ct] - m); ssum += ex[ct]; }
        ssum += __shfl_xor(ssum, 1);
        ssum += __shfl_xor(ssum, 2);
        ssum += __shfl_xor(ssum, 4);
        ssum += __shfl_xor(ssum, 8);
        float is = 1.f / ssum;
        #pragma unroll
        for (int ct = 0; ct < 4; ++ct)
            Pt[l & 63][ct * 16 + rgrp] = f2bf(ex[ct] * is);
    }
    asm volatile("s_waitcnt lgkmcnt(0)" ::: "memory");

    // ---- phase 3: PV (4 MFMAs) + store
    f32x4 oacc[2];
    oacc[0] = (f32x4){0.f, 0.f, 0.f, 0.f};
    oacc[1] = (f32x4){0.f, 0.f, 0.f, 0.f};
    #pragma unroll
    for (int kc = 0; kc < 2; ++kc) {
        bf16x8 pa = *reinterpret_cast<const bf16x8*>(&Pt[16 * wid + rgrp][kc * 32 + kgrp * 8]);
        #pragma unroll
        for (int dt = 0; dt < 2; ++dt) {
            bf16x8 vb = *reinterpret_cast<const bf16x8*>(&Vt[dt * 16 + rgrp][kc * 32 + kgrp * 8]);
            oacc[dt] = __builtin_amdgcn_mfma_f32_16x16x32_bf16(pa, vb, oacc[dt], 0, 0, 0);
        }
    }
    #pragma unroll
    for (int dt = 0; dt < 2; ++dt)
        #pragma unroll
        for (int i = 0; i < 4; ++i) {
            int l = 16 * wid + kgrp * 4 + i;
            if (l <= 48)
                ctx[(size_t)l * lstride + base + dt * 16 + rgrp] = f2bf(oacc[dt][i]);
        }
}

extern "C" void kernel_launch(void* const* d_in, const int* in_sizes, int n_in,
                              void* d_out, int out_size, void* d_ws, size_t ws_size,
                              hipStream_t stream) {
    const float* query = (const float*)d_in[0];
    const float* key   = (const float*)d_in[1];
    const float* value = (const float*)d_in[2];
    const unsigned char* maskp = (const unsigned char*)d_in[3];
    const float* W     = (const float*)d_in[4];   // (768,256)
    const float* bias  = (const float*)d_in[5];   // (768,)
    const float* out_w = (const float*)d_in[6];   // (256,256)
    const float* out_b = (const float*)d_in[7];   // (256,)
    const float* pos_x = (const float*)d_in[8];   // (41,128)
    const float* pos_y = (const float*)d_in[9];   // (41,128)
    float* out = (float*)d_out;

    int B = in_sizes[0] / (L_Q * D_MODEL);        // 2048
    int M = L_Q * B;                              // 100352 = 784 * 128

    size_t nqkv = (size_t)M * D_MODEL;
    unsigned short* qb = (unsigned short*)d_ws;
    unsigned short* kb = qb + nqkv;
    unsigned short* vb = kb + nqkv;
    unsigned short* kpb = vb + nqkv;              // [2][41][256] bf16
    unsigned short* wbf = kpb + 2 * PP * D_MODEL; // 768x256 bf16 (q-rows pre-scaled)
    unsigned short* owbf = wbf + 768 * 256;       // 256x256 bf16

    const float scaling = 0.17677669529663687f;   // 1/sqrt(32)

    convert_w<<<256, 256, 0, stream>>>(W, out_w, scaling, wbf, owbf);
    prep_kpos<<<dim3(PP, 2), 256, 0, stream>>>(pos_y, pos_x, W, kpb);

    int rblocks = M / 128;                        // 784
    proj_mfma<<<dim3(rblocks, 3), 512, 0, stream>>>(query, key, value, wbf, bias, scaling,
                                                    qb, kb, vb);

    attn_mfma<<<dim3(B, NHEAD), 256, 0, stream>>>(qb, kb, vb, kpb, maskp, qb, B);

    out_mfma<<<rblocks, 512, 0, stream>>>(qb, owbf, out_b, out);
}